// Round 5
// baseline (150.666 us; speedup 1.0000x reference)
//
#include <hip/hip_runtime.h>

typedef __attribute__((ext_vector_type(8))) short short8;
typedef __attribute__((ext_vector_type(4))) float floatx4;
typedef __attribute__((ext_vector_type(4))) unsigned uintx4;

#define NTYPES    64
#define WT_STRIDE 5632   // ushorts per type in transposed weight array
#define WROWS     16     // sorted rows per wave (= one MFMA tile)
#define CPAD      16     // counter padding (ints) -> 64B, one cache line per counter

__device__ __forceinline__ unsigned short f2bf(float f) {
    union { float f; unsigned u; } v; v.f = f;
    unsigned u = v.u;
    u += 0x7FFFu + ((u >> 16) & 1u);   // round-to-nearest-even
    return (unsigned short)(u >> 16);
}

// pack two f32 -> two bf16 (RNE), compile-time source selection does the
// d-major fragment permutation in registers (no LDS round-trip).
__device__ __forceinline__ unsigned pk2(float lo, float hi) {
    unsigned r;
    asm("v_cvt_pk_bf16_f32 %0, %1, %2" : "=v"(r) : "v"(lo), "v"(hi));
    return r;
}

// ---- weight transpose: LDS-staged (coalesced global reads), bf16, scale folded ----
// Also zeroes the global type counters (stream-orders before hist_kernel).
// Layout per type (ushorts, base ty*5632):
//   irrep0: f in [0,8): [f*512 + r*32 + k2] = W0[i=(f&1)*32+k2][o=(f>>1)*16+r]*s0
//   irrep1: h in [0,2): [4096 + h*512 + r*32 + k] = W1[i=k][o=h*16+r]*s1
//   irrep2:             [5120 + r*32 + k] (k<16 data, k>=16 zero) = W2[i=k][o=r]*s2
__global__ __launch_bounds__(256) void wt_kernel(const float* __restrict__ W0,
                                                 const float* __restrict__ W1,
                                                 const float* __restrict__ W2,
                                                 unsigned short* __restrict__ wt,
                                                 int* __restrict__ gcount) {
    __shared__ float ws0[4096];
    __shared__ float ws1[1024];
    __shared__ float ws2[256];
    const int t = blockIdx.x, tid = threadIdx.x;
    if (t == 0 && tid < NTYPES) gcount[tid * CPAD] = 0;
    const float4* s0 = (const float4*)(W0 + (size_t)t * 4096);
#pragma unroll
    for (int j = 0; j < 4; ++j) ((float4*)ws0)[j * 256 + tid] = s0[j * 256 + tid];
    ((float4*)ws1)[tid] = ((const float4*)(W1 + (size_t)t * 1024))[tid];
    if (tid < 64) ((float4*)ws2)[tid] = ((const float4*)(W2 + (size_t)t * 256))[tid];
    __syncthreads();
    unsigned short* dst = wt + (size_t)t * WT_STRIDE;
    for (int e = tid; e < 4096; e += 256) {
        int f = e >> 9, rem = e & 511, rr = rem >> 5, k2 = rem & 31;
        int i = (f & 1) * 32 + k2, o = (f >> 1) * 16 + rr;
        dst[e] = f2bf(ws0[i * 64 + o] * 0.125f);
    }
    for (int e = tid; e < 1024; e += 256) {
        int h = e >> 9, rem = e & 511, rr = rem >> 5, k = rem & 31;
        dst[4096 + e] = f2bf(ws1[k * 32 + h * 16 + rr] * 0.17677669529663687f);
    }
    for (int e = tid; e < 512; e += 256) {
        int rr = e >> 5, k = e & 31;
        dst[5120 + e] = (k < 16) ? f2bf(ws2[k * 16 + rr] * 0.25f) : (unsigned short)0;
    }
}

// ---- sort pass 1: per-block LDS histogram -> padded global counters ----
__global__ __launch_bounds__(256) void hist_kernel(const int* __restrict__ idx,
                                                   int* __restrict__ gcount, int n) {
    __shared__ int c[NTYPES];
    const int tid = threadIdx.x, g = blockIdx.x * 256 + tid;
    if (tid < NTYPES) c[tid] = 0;
    __syncthreads();
    if (g < n) atomicAdd(&c[idx[g]], 1);
    __syncthreads();
    if (tid < NTYPES && c[tid]) atomicAdd(&gcount[tid * CPAD], c[tid]);
}

// ---- sort pass 2: one-wave exclusive scan of 64 totals -> global cursors ----
__global__ __launch_bounds__(64) void base_kernel(const int* __restrict__ gcount,
                                                  int* __restrict__ gcur) {
    const int t = threadIdx.x;           // 64 threads = 1 wave
    int v = gcount[t * CPAD];
    int s = v;
#pragma unroll
    for (int o = 1; o < 64; o <<= 1) {
        int u = __shfl_up(s, o);
        if (t >= o) s += u;
    }
    gcur[t * CPAD] = s - v;              // exclusive base
}

// ---- sort pass 3: block reserves a chunk per type, writes packed node|ty<<24 ----
__global__ __launch_bounds__(256) void scatter_kernel(const int* __restrict__ idx,
                                                      int* __restrict__ gcur,
                                                      int* __restrict__ psort, int n) {
    __shared__ int c[NTYPES], off[NTYPES], cur[NTYPES];
    const int tid = threadIdx.x, g = blockIdx.x * 256 + tid;
    if (tid < NTYPES) { c[tid] = 0; cur[tid] = 0; }
    __syncthreads();
    int ty = -1;
    if (g < n) { ty = idx[g]; atomicAdd(&c[ty], 1); }
    __syncthreads();
    if (tid < NTYPES && c[tid]) off[tid] = atomicAdd(&gcur[tid * CPAD], c[tid]);
    __syncthreads();
    if (g < n) {
        int rk = atomicAdd(&cur[ty], 1);
        psort[off[ty] + rk] = g | (ty << 24);
    }
}

// ---- main: 4 independent waves per block (no LDS, no barriers). Each wave owns
// ---- one 16-row sorted window; lane (r,q4) loads its MFMA fragment sources
// ---- DIRECTLY from global x and permutes to d-major bf16 in registers (pk2).
// ---- Segment loop (ballot boundaries) + masked float4 stores, as before.
__global__ __launch_bounds__(256, 4) void main_kernel(
    const float* __restrict__ x,
    const int* __restrict__ psort,
    const unsigned short* __restrict__ wt,
    float* __restrict__ out, int n)
{
    const int tid = threadIdx.x, wv = tid >> 6, ln = tid & 63;
    const int w = blockIdx.x * 4 + wv;        // global wave id
    const int nbase = w * WROWS;
    if (nbase >= n) return;
    const int nv = min(WROWS, n - nbase);

    // packed psort entries for this wave's window live in lanes 0..15
    int pl = 0;
    if (ln < WROWS && (nbase + ln) < n) pl = psort[nbase + ln];

    const int r = ln & 15, q4 = ln >> 4;
    const int prow = __shfl(pl, min(r, nv - 1));
    const int node = prow & 0xFFFFFF;
    const float* xp = x + (size_t)node * 240;

    union frag { short8 s; uintx4 u; };

    // ---- irrep0 fragments: elements i = q4*8 + j (two 32B spans) ----
    float4 f0a = *(const float4*)(xp + q4 * 8);
    float4 f0b = *(const float4*)(xp + q4 * 8 + 4);
    float4 f0c = *(const float4*)(xp + 32 + q4 * 8);
    float4 f0d = *(const float4*)(xp + 32 + q4 * 8 + 4);
    frag bx0, bx1;
    bx0.u = uintx4{pk2(f0a.x, f0a.y), pk2(f0a.z, f0a.w),
                   pk2(f0b.x, f0b.y), pk2(f0b.z, f0b.w)};
    bx1.u = uintx4{pk2(f0c.x, f0c.y), pk2(f0c.z, f0c.w),
                   pk2(f0d.x, f0d.y), pk2(f0d.z, f0d.w)};

    // ---- irrep1: source span x[64 + q4*24 .. +24): elem (i=q4*8+j, d) = G[3j+d] ----
    const float4* xg = (const float4*)(xp + 64 + q4 * 24);
    float4 g0 = xg[0], g1 = xg[1], g2 = xg[2], g3 = xg[3], g4 = xg[4], g5 = xg[5];
    const float G[24] = {g0.x, g0.y, g0.z, g0.w, g1.x, g1.y, g1.z, g1.w,
                         g2.x, g2.y, g2.z, g2.w, g3.x, g3.y, g3.z, g3.w,
                         g4.x, g4.y, g4.z, g4.w, g5.x, g5.y, g5.z, g5.w};
    frag b1d[3];
#pragma unroll
    for (int d = 0; d < 3; ++d)
        b1d[d].u = uintx4{pk2(G[d], G[3 + d]), pk2(G[6 + d], G[9 + d]),
                          pk2(G[12 + d], G[15 + d]), pk2(G[18 + d], G[21 + d])};

    // ---- irrep2: span x[160 + (q4&1)*40 .. +40): elem (i,d) = H[5j+d] ----
    const float4* xh = (const float4*)(xp + 160 + (q4 & 1) * 40);
    float4 h0 = xh[0], h1 = xh[1], h2 = xh[2], h3 = xh[3], h4 = xh[4];
    float4 h5 = xh[5], h6 = xh[6], h7 = xh[7], h8 = xh[8], h9 = xh[9];
    const float H[40] = {h0.x, h0.y, h0.z, h0.w, h1.x, h1.y, h1.z, h1.w,
                         h2.x, h2.y, h2.z, h2.w, h3.x, h3.y, h3.z, h3.w,
                         h4.x, h4.y, h4.z, h4.w, h5.x, h5.y, h5.z, h5.w,
                         h6.x, h6.y, h6.z, h6.w, h7.x, h7.y, h7.z, h7.w,
                         h8.x, h8.y, h8.z, h8.w, h9.x, h9.y, h9.z, h9.w};
    frag b2d[5];
#pragma unroll
    for (int d = 0; d < 5; ++d)
        b2d[d].u = uintx4{pk2(H[d], H[5 + d]), pk2(H[10 + d], H[15 + d]),
                          pk2(H[20 + d], H[25 + d]), pk2(H[30 + d], H[35 + d])};

    const bool vrow = (r < nv);
    float* op = out + (size_t)node * 240;

    // ---- segment detection within the 16-row window (usually 1 segment) ----
    int ti  = __shfl(pl, r) >> 24;
    int tim = __shfl(pl, (r > 0) ? (r - 1) : 0) >> 24;
    bool bnd = (r == 0) || (ti != tim);
    unsigned m = (unsigned)(__ballot(bnd) & 0xFFFFull);

    while (m) {
        const int slo = __builtin_ctz(m);
        const unsigned m2 = m & (m - 1u);
        const int shi = m2 ? __builtin_ctz(m2) : nv;
        const int tyseg = __shfl(pl, slo) >> 24;
        const unsigned short* wb = wt + (size_t)tyseg * WT_STRIDE;
        const bool vst = vrow && (r >= slo) && (r < shi);

        // ---- irrep0: D[o=nt*16+q4*4+reg][node=r], K=64 ----
#pragma unroll
        for (int nt = 0; nt < 4; ++nt) {
            short8 wa = *(const short8*)(wb + (nt * 2) * 512 + r * 32 + q4 * 8);
            short8 wc = *(const short8*)(wb + (nt * 2 + 1) * 512 + r * 32 + q4 * 8);
            floatx4 ac = {0.f, 0.f, 0.f, 0.f};
            ac = __builtin_amdgcn_mfma_f32_16x16x32_bf16(wa, bx0.s, ac, 0, 0, 0);
            ac = __builtin_amdgcn_mfma_f32_16x16x32_bf16(wc, bx1.s, ac, 0, 0, 0);
            if (vst) *(floatx4*)(op + nt * 16 + q4 * 4) = ac;   // 4 consecutive o
        }

        // ---- irrep1: per d, 2 M-tiles; store 12 consecutive floats as 3x float4 ----
        {
            short8 wc0 = *(const short8*)(wb + 4096 + r * 32 + q4 * 8);
            short8 wc1 = *(const short8*)(wb + 4096 + 512 + r * 32 + q4 * 8);
            floatx4 a1[2][3];
#pragma unroll
            for (int d = 0; d < 3; ++d) {
                floatx4 z = {0.f, 0.f, 0.f, 0.f};
                a1[0][d] = __builtin_amdgcn_mfma_f32_16x16x32_bf16(wc0, b1d[d].s, z, 0, 0, 0);
                a1[1][d] = __builtin_amdgcn_mfma_f32_16x16x32_bf16(wc1, b1d[d].s, z, 0, 0, 0);
            }
            if (vst) {
#pragma unroll
                for (int h = 0; h < 2; ++h) {
                    float* o1 = op + 64 + (h * 16 + q4 * 4) * 3;
                    floatx4 v0 = {a1[h][0][0], a1[h][1][0], a1[h][2][0], a1[h][0][1]};
                    floatx4 v1 = {a1[h][1][1], a1[h][2][1], a1[h][0][2], a1[h][1][2]};
                    floatx4 v2 = {a1[h][2][2], a1[h][0][3], a1[h][1][3], a1[h][2][3]};
                    *(floatx4*)(o1)     = v0;
                    *(floatx4*)(o1 + 4) = v1;
                    *(floatx4*)(o1 + 8) = v2;
                }
            }
        }

        // ---- irrep2: per d, M=16 K=16 (w-side zero-padded to K=32); 5x float4 ----
        {
            short8 wc2 = *(const short8*)(wb + 5120 + r * 32 + q4 * 8);
            floatx4 a2[5];
#pragma unroll
            for (int d = 0; d < 5; ++d) {
                floatx4 z = {0.f, 0.f, 0.f, 0.f};
                a2[d] = __builtin_amdgcn_mfma_f32_16x16x32_bf16(wc2, b2d[d].s, z, 0, 0, 0);
            }
            if (vst) {
                float* o2 = op + 160 + q4 * 20;
                floatx4 v0 = {a2[0][0], a2[1][0], a2[2][0], a2[3][0]};
                floatx4 v1 = {a2[4][0], a2[0][1], a2[1][1], a2[2][1]};
                floatx4 v2 = {a2[3][1], a2[4][1], a2[0][2], a2[1][2]};
                floatx4 v3 = {a2[2][2], a2[3][2], a2[4][2], a2[0][3]};
                floatx4 v4 = {a2[1][3], a2[2][3], a2[3][3], a2[4][3]};
                *(floatx4*)(o2)      = v0;
                *(floatx4*)(o2 + 4)  = v1;
                *(floatx4*)(o2 + 8)  = v2;
                *(floatx4*)(o2 + 12) = v3;
                *(floatx4*)(o2 + 16) = v4;
            }
        }
        m = m2;
    }
}

extern "C" void kernel_launch(void* const* d_in, const int* in_sizes, int n_in,
                              void* d_out, int out_size, void* d_ws, size_t ws_size,
                              hipStream_t stream) {
    const float* x  = (const float*)d_in[0];
    const float* W0 = (const float*)d_in[1];
    const float* W1 = (const float*)d_in[2];
    const float* W2 = (const float*)d_in[3];
    const int*   idx = (const int*)d_in[4];
    float* out = (float*)d_out;
    const int n = in_sizes[4];                    // 65536 nodes
    const int nb = (n + 255) / 256;

    char* ws = (char*)d_ws;
    unsigned short* wt = (unsigned short*)ws;     // 720896 B
    size_t off = (size_t)NTYPES * WT_STRIDE * 2;
    int* psort  = (int*)(ws + off); off += (size_t)n * 4;
    int* gcount = (int*)(ws + off); off += (size_t)NTYPES * CPAD * 4;
    int* gcur   = (int*)(ws + off);

    wt_kernel     <<<NTYPES, 256, 0, stream>>>(W0, W1, W2, wt, gcount);
    hist_kernel   <<<nb, 256, 0, stream>>>(idx, gcount, n);
    base_kernel   <<<1, 64, 0, stream>>>(gcount, gcur);
    scatter_kernel<<<nb, 256, 0, stream>>>(idx, gcur, psort, n);
    main_kernel   <<<(n + 4 * WROWS - 1) / (4 * WROWS), 256, 0, stream>>>(x, psort, wt, out, n);
}

// Round 8
// 149.868 us; speedup vs baseline: 1.0053x; 1.0053x over previous
//
#include <hip/hip_runtime.h>

typedef __attribute__((ext_vector_type(8))) short short8;
typedef __attribute__((ext_vector_type(4))) float floatx4;
typedef __attribute__((ext_vector_type(4))) unsigned uintx4;

#define NTYPES    64
#define WT_STRIDE 5632   // ushorts per type in transposed weight array
#define WROWS     16     // sorted rows per wave (= one MFMA tile)
#define CPAD      16     // counter padding (ints) -> 64B, one cache line per counter

__device__ __forceinline__ unsigned short f2bf(float f) {
    union { float f; unsigned u; } v; v.f = f;
    unsigned u = v.u;
    u += 0x7FFFu + ((u >> 16) & 1u);   // round-to-nearest-even
    return (unsigned short)(u >> 16);
}

// pack two f32 -> two bf16 (RNE); compile-time source selection does the
// d-major fragment permutation in registers.
__device__ __forceinline__ unsigned pk2(float lo, float hi) {
    unsigned r;
    asm("v_cvt_pk_bf16_f32 %0, %1, %2" : "=v"(r) : "v"(lo), "v"(hi));
    return r;
}

// ---- weight transpose (LDS-staged, bf16, scale folded) + partial histogram ----
// Each of the 64 blocks also histograms a 1/64 slice of idx into bh[b][64]
// (plain stores -> no zero-init needed under workspace poisoning).
// wt layout per type (ushorts, base ty*5632):
//   irrep0: f in [0,8): [f*512 + r*32 + k2] = W0[i=(f&1)*32+k2][o=(f>>1)*16+r]*s0
//   irrep1: h in [0,2): [4096 + h*512 + r*32 + k] = W1[i=k][o=h*16+r]*s1
//   irrep2:             [5120 + r*32 + k] (k<16 data, k>=16 zero) = W2[i=k][o=r]*s2
__global__ __launch_bounds__(256) void wt_kernel(const float* __restrict__ W0,
                                                 const float* __restrict__ W1,
                                                 const float* __restrict__ W2,
                                                 const int* __restrict__ idx,
                                                 unsigned short* __restrict__ wt,
                                                 int* __restrict__ bh, int n) {
    __shared__ float ws0[4096];
    __shared__ float ws1[1024];
    __shared__ float ws2[256];
    __shared__ int hc[NTYPES];
    const int t = blockIdx.x, tid = threadIdx.x;
    if (tid < NTYPES) hc[tid] = 0;
    const float4* s0 = (const float4*)(W0 + (size_t)t * 4096);
#pragma unroll
    for (int j = 0; j < 4; ++j) ((float4*)ws0)[j * 256 + tid] = s0[j * 256 + tid];
    ((float4*)ws1)[tid] = ((const float4*)(W1 + (size_t)t * 1024))[tid];
    if (tid < 64) ((float4*)ws2)[tid] = ((const float4*)(W2 + (size_t)t * 256))[tid];
    __syncthreads();
    // histogram slice [t*per, (t+1)*per)
    const int per = (n + NTYPES - 1) / NTYPES;
    for (int e = tid; e < per; e += 256) {
        int g = t * per + e;
        if (g < n) atomicAdd(&hc[idx[g]], 1);
    }
    unsigned short* dst = wt + (size_t)t * WT_STRIDE;
    for (int e = tid; e < 4096; e += 256) {
        int f = e >> 9, rem = e & 511, rr = rem >> 5, k2 = rem & 31;
        int i = (f & 1) * 32 + k2, o = (f >> 1) * 16 + rr;
        dst[e] = f2bf(ws0[i * 64 + o] * 0.125f);
    }
    for (int e = tid; e < 1024; e += 256) {
        int h = e >> 9, rem = e & 511, rr = rem >> 5, k = rem & 31;
        dst[4096 + e] = f2bf(ws1[k * 32 + h * 16 + rr] * 0.17677669529663687f);
    }
    for (int e = tid; e < 512; e += 256) {
        int rr = e >> 5, k = e & 31;
        dst[5120 + e] = (k < 16) ? f2bf(ws2[k * 16 + rr] * 0.25f) : (unsigned short)0;
    }
    __syncthreads();
    if (tid < NTYPES) bh[t * NTYPES + tid] = hc[tid];
}

// ---- sort pass 2: sum 64 partial hists, one-wave exclusive scan -> cursors ----
__global__ __launch_bounds__(64) void base_kernel(const int* __restrict__ bh,
                                                  int* __restrict__ gcur) {
    const int t = threadIdx.x;           // 64 threads = 1 wave
    int v = 0;
#pragma unroll
    for (int b = 0; b < NTYPES; ++b) v += bh[b * NTYPES + t];   // independent loads
    int s = v;
#pragma unroll
    for (int o = 1; o < 64; o <<= 1) {
        int u = __shfl_up(s, o);
        if (t >= o) s += u;
    }
    gcur[t * CPAD] = s - v;              // exclusive base
}

// ---- sort pass 3: block reserves a chunk per type, writes packed node|ty<<24 ----
__global__ __launch_bounds__(256) void scatter_kernel(const int* __restrict__ idx,
                                                      int* __restrict__ gcur,
                                                      int* __restrict__ psort, int n) {
    __shared__ int c[NTYPES], off[NTYPES], cur[NTYPES];
    const int tid = threadIdx.x, g = blockIdx.x * 256 + tid;
    if (tid < NTYPES) { c[tid] = 0; cur[tid] = 0; }
    __syncthreads();
    int ty = -1;
    if (g < n) { ty = idx[g]; atomicAdd(&c[ty], 1); }
    __syncthreads();
    if (tid < NTYPES && c[tid]) off[tid] = atomicAdd(&gcur[tid * CPAD], c[tid]);
    __syncthreads();
    if (g < n) {
        int rk = atomicAdd(&cur[ty], 1);
        psort[off[ty] + rk] = g | (ty << 24);
    }
}

// weight-fragment load cluster (11 x b128 from one type's table)
#define LOAD_FRAGS(WB) do {                                         \
    const unsigned short* _wp = (WB) + r * 32 + q4 * 8;             \
    wa0 = *(const short8*)(_wp);                                    \
    wa1 = *(const short8*)(_wp + 512);                              \
    wa2 = *(const short8*)(_wp + 1024);                             \
    wa3 = *(const short8*)(_wp + 1536);                             \
    wa4 = *(const short8*)(_wp + 2048);                             \
    wa5 = *(const short8*)(_wp + 2560);                             \
    wa6 = *(const short8*)(_wp + 3072);                             \
    wa7 = *(const short8*)(_wp + 3584);                             \
    wc0 = *(const short8*)(_wp + 4096);                             \
    wc1 = *(const short8*)(_wp + 4608);                             \
    wc2 = *(const short8*)(_wp + 5120);                             \
} while (0)

// ---- main: 4 independent waves/block, no LDS/barriers. Deep load clustering:
// ---- ALL 20 x-loads + 11 first-segment weight loads issue into distinct regs
// ---- in ONE vmcnt group (sched_barrier pins them above the converts), then
// ---- register bf16 permute (pk2) + 19 MFMAs + float4 stores.
__global__ __launch_bounds__(256, 3) void main_kernel(
    const float* __restrict__ x,
    const int* __restrict__ psort,
    const unsigned short* __restrict__ wt,
    float* __restrict__ out, int n)
{
    const int tid = threadIdx.x, wv = tid >> 6, ln = tid & 63;
    const int w = blockIdx.x * 4 + wv;        // global wave id
    const int nbase = w * WROWS;
    if (nbase >= n) return;
    const int nv = min(WROWS, n - nbase);

    // packed psort entries for this wave's window live in lanes 0..15
    int pl = 0;
    if (ln < WROWS && (nbase + ln) < n) pl = psort[nbase + ln];

    const int r = ln & 15, q4 = ln >> 4;
    const int prow = __shfl(pl, min(r, nv - 1));
    const int node = prow & 0xFFFFFF;
    const float* xp = x + (size_t)node * 240;

    // ---- segment structure first (needs only pl) so seg0 weights co-issue ----
    int ti  = __shfl(pl, r) >> 24;
    int tim = __shfl(pl, (r > 0) ? (r - 1) : 0) >> 24;
    bool bnd = (r == 0) || (ti != tim);
    unsigned m = (unsigned)(__ballot(bnd) & 0xFFFFull);   // bit 0 always set
    const int ty0 = __shfl(pl, 0) >> 24;

    // ---- issue ALL loads (20 x float4 + 11 weight b128) ----
    float4 f0a = *(const float4*)(xp + q4 * 8);
    float4 f0b = *(const float4*)(xp + q4 * 8 + 4);
    float4 f0c = *(const float4*)(xp + 32 + q4 * 8);
    float4 f0d = *(const float4*)(xp + 32 + q4 * 8 + 4);
    const float4* xg = (const float4*)(xp + 64 + q4 * 24);
    float4 g0 = xg[0], g1 = xg[1], g2 = xg[2], g3 = xg[3], g4 = xg[4], g5 = xg[5];
    const float4* xh = (const float4*)(xp + 160 + (q4 & 1) * 40);
    float4 h0 = xh[0], h1 = xh[1], h2 = xh[2], h3 = xh[3], h4 = xh[4];
    float4 h5 = xh[5], h6 = xh[6], h7 = xh[7], h8 = xh[8], h9 = xh[9];
    short8 wa0, wa1, wa2, wa3, wa4, wa5, wa6, wa7, wc0, wc1, wc2;
    LOAD_FRAGS(wt + (size_t)ty0 * WT_STRIDE);
    __builtin_amdgcn_sched_barrier(0);   // keep the load cluster above consumers

    union frag { short8 s; uintx4 u; };

    // ---- register permute to MFMA B-fragments (bf16) ----
    frag bx0, bx1;
    bx0.u = uintx4{pk2(f0a.x, f0a.y), pk2(f0a.z, f0a.w),
                   pk2(f0b.x, f0b.y), pk2(f0b.z, f0b.w)};
    bx1.u = uintx4{pk2(f0c.x, f0c.y), pk2(f0c.z, f0c.w),
                   pk2(f0d.x, f0d.y), pk2(f0d.z, f0d.w)};
    const float G[24] = {g0.x, g0.y, g0.z, g0.w, g1.x, g1.y, g1.z, g1.w,
                         g2.x, g2.y, g2.z, g2.w, g3.x, g3.y, g3.z, g3.w,
                         g4.x, g4.y, g4.z, g4.w, g5.x, g5.y, g5.z, g5.w};
    frag b1d[3];
#pragma unroll
    for (int d = 0; d < 3; ++d)
        b1d[d].u = uintx4{pk2(G[d], G[3 + d]), pk2(G[6 + d], G[9 + d]),
                          pk2(G[12 + d], G[15 + d]), pk2(G[18 + d], G[21 + d])};
    const float H[40] = {h0.x, h0.y, h0.z, h0.w, h1.x, h1.y, h1.z, h1.w,
                         h2.x, h2.y, h2.z, h2.w, h3.x, h3.y, h3.z, h3.w,
                         h4.x, h4.y, h4.z, h4.w, h5.x, h5.y, h5.z, h5.w,
                         h6.x, h6.y, h6.z, h6.w, h7.x, h7.y, h7.z, h7.w,
                         h8.x, h8.y, h8.z, h8.w, h9.x, h9.y, h9.z, h9.w};
    frag b2d[5];
#pragma unroll
    for (int d = 0; d < 5; ++d)
        b2d[d].u = uintx4{pk2(H[d], H[5 + d]), pk2(H[10 + d], H[15 + d]),
                          pk2(H[20 + d], H[25 + d]), pk2(H[30 + d], H[35 + d])};

    const bool vrow = (r < nv);
    float* op = out + (size_t)node * 240;

    while (true) {
        const int slo = __builtin_ctz(m);
        const unsigned m2 = m & (m - 1u);
        const int shi = m2 ? __builtin_ctz(m2) : nv;
        const bool vst = vrow && (r >= slo) && (r < shi);

        // ---- irrep0: D[o=nt*16+q4*4+reg][node=r], K=64 ----
        {
            floatx4 ac;
            ac = floatx4{0.f, 0.f, 0.f, 0.f};
            ac = __builtin_amdgcn_mfma_f32_16x16x32_bf16(wa0, bx0.s, ac, 0, 0, 0);
            ac = __builtin_amdgcn_mfma_f32_16x16x32_bf16(wa1, bx1.s, ac, 0, 0, 0);
            if (vst) *(floatx4*)(op + q4 * 4) = ac;
            ac = floatx4{0.f, 0.f, 0.f, 0.f};
            ac = __builtin_amdgcn_mfma_f32_16x16x32_bf16(wa2, bx0.s, ac, 0, 0, 0);
            ac = __builtin_amdgcn_mfma_f32_16x16x32_bf16(wa3, bx1.s, ac, 0, 0, 0);
            if (vst) *(floatx4*)(op + 16 + q4 * 4) = ac;
            ac = floatx4{0.f, 0.f, 0.f, 0.f};
            ac = __builtin_amdgcn_mfma_f32_16x16x32_bf16(wa4, bx0.s, ac, 0, 0, 0);
            ac = __builtin_amdgcn_mfma_f32_16x16x32_bf16(wa5, bx1.s, ac, 0, 0, 0);
            if (vst) *(floatx4*)(op + 32 + q4 * 4) = ac;
            ac = floatx4{0.f, 0.f, 0.f, 0.f};
            ac = __builtin_amdgcn_mfma_f32_16x16x32_bf16(wa6, bx0.s, ac, 0, 0, 0);
            ac = __builtin_amdgcn_mfma_f32_16x16x32_bf16(wa7, bx1.s, ac, 0, 0, 0);
            if (vst) *(floatx4*)(op + 48 + q4 * 4) = ac;
        }

        // ---- irrep1: per d, 2 M-tiles; 12 consecutive floats as 3x float4 ----
        {
            floatx4 a1[2][3];
#pragma unroll
            for (int d = 0; d < 3; ++d) {
                floatx4 z = {0.f, 0.f, 0.f, 0.f};
                a1[0][d] = __builtin_amdgcn_mfma_f32_16x16x32_bf16(wc0, b1d[d].s, z, 0, 0, 0);
                a1[1][d] = __builtin_amdgcn_mfma_f32_16x16x32_bf16(wc1, b1d[d].s, z, 0, 0, 0);
            }
            if (vst) {
#pragma unroll
                for (int h = 0; h < 2; ++h) {
                    float* o1 = op + 64 + (h * 16 + q4 * 4) * 3;
                    floatx4 v0 = {a1[h][0][0], a1[h][1][0], a1[h][2][0], a1[h][0][1]};
                    floatx4 v1 = {a1[h][1][1], a1[h][2][1], a1[h][0][2], a1[h][1][2]};
                    floatx4 v2 = {a1[h][2][2], a1[h][0][3], a1[h][1][3], a1[h][2][3]};
                    *(floatx4*)(o1)     = v0;
                    *(floatx4*)(o1 + 4) = v1;
                    *(floatx4*)(o1 + 8) = v2;
                }
            }
        }

        // ---- irrep2: per d, M=16 K=16 (w-side zero-padded to K=32); 5x float4 ----
        {
            floatx4 a2[5];
#pragma unroll
            for (int d = 0; d < 5; ++d) {
                floatx4 z = {0.f, 0.f, 0.f, 0.f};
                a2[d] = __builtin_amdgcn_mfma_f32_16x16x32_bf16(wc2, b2d[d].s, z, 0, 0, 0);
            }
            if (vst) {
                float* o2 = op + 160 + q4 * 20;
                floatx4 v0 = {a2[0][0], a2[1][0], a2[2][0], a2[3][0]};
                floatx4 v1 = {a2[4][0], a2[0][1], a2[1][1], a2[2][1]};
                floatx4 v2 = {a2[3][1], a2[4][1], a2[0][2], a2[1][2]};
                floatx4 v3 = {a2[2][2], a2[3][2], a2[4][2], a2[0][3]};
                floatx4 v4 = {a2[1][3], a2[2][3], a2[3][3], a2[4][3]};
                *(floatx4*)(o2)      = v0;
                *(floatx4*)(o2 + 4)  = v1;
                *(floatx4*)(o2 + 8)  = v2;
                *(floatx4*)(o2 + 12) = v3;
                *(floatx4*)(o2 + 16) = v4;
            }
        }

        m = m2;
        if (!m) break;
        const int tyn = __shfl(pl, __builtin_ctz(m)) >> 24;   // rare: next segment
        LOAD_FRAGS(wt + (size_t)tyn * WT_STRIDE);
    }
}

extern "C" void kernel_launch(void* const* d_in, const int* in_sizes, int n_in,
                              void* d_out, int out_size, void* d_ws, size_t ws_size,
                              hipStream_t stream) {
    const float* x  = (const float*)d_in[0];
    const float* W0 = (const float*)d_in[1];
    const float* W1 = (const float*)d_in[2];
    const float* W2 = (const float*)d_in[3];
    const int*   idx = (const int*)d_in[4];
    float* out = (float*)d_out;
    const int n = in_sizes[4];                    // 65536 nodes
    const int nb = (n + 255) / 256;

    char* ws = (char*)d_ws;
    unsigned short* wt = (unsigned short*)ws;     // 720896 B
    size_t off = (size_t)NTYPES * WT_STRIDE * 2;
    int* psort = (int*)(ws + off); off += (size_t)n * 4;
    int* bh    = (int*)(ws + off); off += (size_t)NTYPES * NTYPES * 4;
    int* gcur  = (int*)(ws + off);

    wt_kernel     <<<NTYPES, 256, 0, stream>>>(W0, W1, W2, idx, wt, bh, n);
    base_kernel   <<<1, 64, 0, stream>>>(bh, gcur);
    scatter_kernel<<<nb, 256, 0, stream>>>(idx, gcur, psort, n);
    main_kernel   <<<(n + 4 * WROWS - 1) / (4 * WROWS), 256, 0, stream>>>(x, psort, wt, out, n);
}

// Round 9
// 143.551 us; speedup vs baseline: 1.0496x; 1.0440x over previous
//
#include <hip/hip_runtime.h>

typedef __attribute__((ext_vector_type(8))) short short8;
typedef __attribute__((ext_vector_type(4))) float floatx4;
typedef __attribute__((ext_vector_type(4))) unsigned uintx4;

#define NTYPES    64
#define WT_STRIDE 5632   // ushorts per type in transposed weight array
#define WROWS     16     // sorted rows per wave (= one MFMA tile)
#define CPAD      16     // counter padding (ints) -> 64B, one cache line per counter
#define RSTRIDE   976    // padded LDS row stride bytes (61*16: 2-way banks = free)

__device__ __forceinline__ unsigned short f2bf(float f) {
    union { float f; unsigned u; } v; v.f = f;
    unsigned u = v.u;
    u += 0x7FFFu + ((u >> 16) & 1u);   // round-to-nearest-even
    return (unsigned short)(u >> 16);
}

// pack two f32 -> two bf16 (RNE); compile-time source selection does the
// d-major fragment permutation in registers.
__device__ __forceinline__ unsigned pk2(float lo, float hi) {
    unsigned r;
    asm("v_cvt_pk_bf16_f32 %0, %1, %2" : "=v"(r) : "v"(lo), "v"(hi));
    return r;
}

// ---- weight transpose (LDS-staged, bf16, scale folded) + partial histogram ----
__global__ __launch_bounds__(256) void wt_kernel(const float* __restrict__ W0,
                                                 const float* __restrict__ W1,
                                                 const float* __restrict__ W2,
                                                 const int* __restrict__ idx,
                                                 unsigned short* __restrict__ wt,
                                                 int* __restrict__ bh, int n) {
    __shared__ float ws0[4096];
    __shared__ float ws1[1024];
    __shared__ float ws2[256];
    __shared__ int hc[NTYPES];
    const int t = blockIdx.x, tid = threadIdx.x;
    if (tid < NTYPES) hc[tid] = 0;
    const float4* s0 = (const float4*)(W0 + (size_t)t * 4096);
#pragma unroll
    for (int j = 0; j < 4; ++j) ((float4*)ws0)[j * 256 + tid] = s0[j * 256 + tid];
    ((float4*)ws1)[tid] = ((const float4*)(W1 + (size_t)t * 1024))[tid];
    if (tid < 64) ((float4*)ws2)[tid] = ((const float4*)(W2 + (size_t)t * 256))[tid];
    __syncthreads();
    const int per = (n + NTYPES - 1) / NTYPES;
    for (int e = tid; e < per; e += 256) {
        int g = t * per + e;
        if (g < n) atomicAdd(&hc[idx[g]], 1);
    }
    unsigned short* dst = wt + (size_t)t * WT_STRIDE;
    for (int e = tid; e < 4096; e += 256) {
        int f = e >> 9, rem = e & 511, rr = rem >> 5, k2 = rem & 31;
        int i = (f & 1) * 32 + k2, o = (f >> 1) * 16 + rr;
        dst[e] = f2bf(ws0[i * 64 + o] * 0.125f);
    }
    for (int e = tid; e < 1024; e += 256) {
        int h = e >> 9, rem = e & 511, rr = rem >> 5, k = rem & 31;
        dst[4096 + e] = f2bf(ws1[k * 32 + h * 16 + rr] * 0.17677669529663687f);
    }
    for (int e = tid; e < 512; e += 256) {
        int rr = e >> 5, k = e & 31;
        dst[5120 + e] = (k < 16) ? f2bf(ws2[k * 16 + rr] * 0.25f) : (unsigned short)0;
    }
    __syncthreads();
    if (tid < NTYPES) bh[t * NTYPES + tid] = hc[tid];
}

// ---- sort pass 2: sum 64 partial hists, one-wave exclusive scan -> cursors ----
__global__ __launch_bounds__(64) void base_kernel(const int* __restrict__ bh,
                                                  int* __restrict__ gcur) {
    const int t = threadIdx.x;
    int v = 0;
#pragma unroll
    for (int b = 0; b < NTYPES; ++b) v += bh[b * NTYPES + t];
    int s = v;
#pragma unroll
    for (int o = 1; o < 64; o <<= 1) {
        int u = __shfl_up(s, o);
        if (t >= o) s += u;
    }
    gcur[t * CPAD] = s - v;
}

// ---- sort pass 3: block reserves a chunk per type, writes packed node|ty<<24 ----
__global__ __launch_bounds__(256) void scatter_kernel(const int* __restrict__ idx,
                                                      int* __restrict__ gcur,
                                                      int* __restrict__ psort, int n) {
    __shared__ int c[NTYPES], off[NTYPES], cur[NTYPES];
    const int tid = threadIdx.x, g = blockIdx.x * 256 + tid;
    if (tid < NTYPES) { c[tid] = 0; cur[tid] = 0; }
    __syncthreads();
    int ty = -1;
    if (g < n) { ty = idx[g]; atomicAdd(&c[ty], 1); }
    __syncthreads();
    if (tid < NTYPES && c[tid]) off[tid] = atomicAdd(&gcur[tid * CPAD], c[tid]);
    __syncthreads();
    if (g < n) {
        int rk = atomicAdd(&cur[ty], 1);
        psort[off[ty] + rk] = g | (ty << 24);
    }
}

// weight-fragment load cluster (11 x b128 from one type's table)
#define LOAD_FRAGS(WB) do {                                         \
    const unsigned short* _wp = (WB) + r * 32 + q4 * 8;             \
    wa0 = *(const short8*)(_wp);                                    \
    wa1 = *(const short8*)(_wp + 512);                              \
    wa2 = *(const short8*)(_wp + 1024);                             \
    wa3 = *(const short8*)(_wp + 1536);                             \
    wa4 = *(const short8*)(_wp + 2048);                             \
    wa5 = *(const short8*)(_wp + 2560);                             \
    wa6 = *(const short8*)(_wp + 3072);                             \
    wa7 = *(const short8*)(_wp + 3584);                             \
    wc0 = *(const short8*)(_wp + 4096);                             \
    wc1 = *(const short8*)(_wp + 4608);                             \
    wc2 = *(const short8*)(_wp + 5120);                             \
} while (0)

// ---- main: 1 wave / 16 sorted rows. Staging via async global_load_lds
// ---- (gathered per-lane source, linear LDS dest, ZERO VGPR cost -> all 16
// ---- row-loads in flight at once). LDS rows padded to 976B (2-way banks).
// ---- Then 20 aligned ds_read_b128 -> pk2 register permute -> 19 MFMAs.
__global__ __launch_bounds__(64) void main_kernel(
    const float* __restrict__ x,
    const int* __restrict__ psort,
    const unsigned short* __restrict__ wt,
    float* __restrict__ out, int n)
{
    __shared__ __align__(16) unsigned char xl[16384];
    const int ln = threadIdx.x;
    const int nbase = blockIdx.x * WROWS;
    if (nbase >= n) return;
    const int nv = min(WROWS, n - nbase);

    int pl = 0;
    if (ln < WROWS && (nbase + ln) < n) pl = psort[nbase + ln];

    const int r = ln & 15, q4 = ln >> 4;

    // segment structure (needs only pl)
    int ti  = __shfl(pl, r) >> 24;
    int tim = __shfl(pl, (r > 0) ? (r - 1) : 0) >> 24;
    bool bnd = (r == 0) || (ti != tim);
    unsigned m = (unsigned)(__ballot(bnd) & 0xFFFFull);
    const int ty0 = __shfl(pl, 0) >> 24;

    // ---- async stage: 16 x 1KB global->LDS. LDS byte L maps to row L/976,
    // ---- col L%976 (cols >=960 are pad; source clamped). /976 exact via
    // ---- (L>>4)*1075>>16 for L<16384.
#pragma unroll
    for (int k = 0; k < 16; ++k) {
        int L = k * 1024 + ln * 16;
        int row = (int)(((unsigned)(L >> 4) * 1075u) >> 16);
        int col = L - row * RSTRIDE;
        int node = __shfl(pl, min(row, 15)) & 0xFFFFFF;
        int colc = min(col, 944);
        const float* src = x + (size_t)node * 240 + (colc >> 2);
        __builtin_amdgcn_global_load_lds(
            (const __attribute__((address_space(1))) void*)src,
            (__attribute__((address_space(3))) void*)(xl + k * 1024),
            16, 0, 0);
    }

    // first-segment weights issue under the staging latency
    short8 wa0, wa1, wa2, wa3, wa4, wa5, wa6, wa7, wc0, wc1, wc2;
    LOAD_FRAGS(wt + (size_t)ty0 * WT_STRIDE);

    asm volatile("s_waitcnt vmcnt(0)" ::: "memory");
    __builtin_amdgcn_sched_barrier(0);

    // ---- LDS -> f32 fragment sources (all 16B-aligned b128) ----
    const float4* xr = (const float4*)(xl + r * RSTRIDE);
    float4 f0a = xr[q4 * 2],     f0b = xr[q4 * 2 + 1];
    float4 f0c = xr[8 + q4 * 2], f0d = xr[9 + q4 * 2];
    float4 g0 = xr[16 + q4 * 6],     g1 = xr[16 + q4 * 6 + 1], g2 = xr[16 + q4 * 6 + 2];
    float4 g3 = xr[16 + q4 * 6 + 3], g4 = xr[16 + q4 * 6 + 4], g5 = xr[16 + q4 * 6 + 5];
    const int hb = 40 + (q4 & 1) * 10;
    float4 h0 = xr[hb],     h1 = xr[hb + 1], h2 = xr[hb + 2], h3 = xr[hb + 3];
    float4 h4 = xr[hb + 4], h5 = xr[hb + 5], h6 = xr[hb + 6], h7 = xr[hb + 7];
    float4 h8 = xr[hb + 8], h9 = xr[hb + 9];

    union frag { short8 s; uintx4 u; };

    // ---- register permute to MFMA B-fragments (bf16) ----
    frag bx0, bx1;
    bx0.u = uintx4{pk2(f0a.x, f0a.y), pk2(f0a.z, f0a.w),
                   pk2(f0b.x, f0b.y), pk2(f0b.z, f0b.w)};
    bx1.u = uintx4{pk2(f0c.x, f0c.y), pk2(f0c.z, f0c.w),
                   pk2(f0d.x, f0d.y), pk2(f0d.z, f0d.w)};
    const float G[24] = {g0.x, g0.y, g0.z, g0.w, g1.x, g1.y, g1.z, g1.w,
                         g2.x, g2.y, g2.z, g2.w, g3.x, g3.y, g3.z, g3.w,
                         g4.x, g4.y, g4.z, g4.w, g5.x, g5.y, g5.z, g5.w};
    frag b1d[3];
#pragma unroll
    for (int d = 0; d < 3; ++d)
        b1d[d].u = uintx4{pk2(G[d], G[3 + d]), pk2(G[6 + d], G[9 + d]),
                          pk2(G[12 + d], G[15 + d]), pk2(G[18 + d], G[21 + d])};
    const float H[40] = {h0.x, h0.y, h0.z, h0.w, h1.x, h1.y, h1.z, h1.w,
                         h2.x, h2.y, h2.z, h2.w, h3.x, h3.y, h3.z, h3.w,
                         h4.x, h4.y, h4.z, h4.w, h5.x, h5.y, h5.z, h5.w,
                         h6.x, h6.y, h6.z, h6.w, h7.x, h7.y, h7.z, h7.w,
                         h8.x, h8.y, h8.z, h8.w, h9.x, h9.y, h9.z, h9.w};
    frag b2d[5];
#pragma unroll
    for (int d = 0; d < 5; ++d)
        b2d[d].u = uintx4{pk2(H[d], H[5 + d]), pk2(H[10 + d], H[15 + d]),
                          pk2(H[20 + d], H[25 + d]), pk2(H[30 + d], H[35 + d])};

    const bool vrow = (r < nv);
    const int node_r = __shfl(pl, min(r, nv - 1)) & 0xFFFFFF;
    float* op = out + (size_t)node_r * 240;

    while (true) {
        const int slo = __builtin_ctz(m);
        const unsigned m2 = m & (m - 1u);
        const int shi = m2 ? __builtin_ctz(m2) : nv;
        const bool vst = vrow && (r >= slo) && (r < shi);

        // ---- irrep0: D[o=nt*16+q4*4+reg][node=r], K=64 ----
        {
            floatx4 ac;
            ac = floatx4{0.f, 0.f, 0.f, 0.f};
            ac = __builtin_amdgcn_mfma_f32_16x16x32_bf16(wa0, bx0.s, ac, 0, 0, 0);
            ac = __builtin_amdgcn_mfma_f32_16x16x32_bf16(wa1, bx1.s, ac, 0, 0, 0);
            if (vst) *(floatx4*)(op + q4 * 4) = ac;
            ac = floatx4{0.f, 0.f, 0.f, 0.f};
            ac = __builtin_amdgcn_mfma_f32_16x16x32_bf16(wa2, bx0.s, ac, 0, 0, 0);
            ac = __builtin_amdgcn_mfma_f32_16x16x32_bf16(wa3, bx1.s, ac, 0, 0, 0);
            if (vst) *(floatx4*)(op + 16 + q4 * 4) = ac;
            ac = floatx4{0.f, 0.f, 0.f, 0.f};
            ac = __builtin_amdgcn_mfma_f32_16x16x32_bf16(wa4, bx0.s, ac, 0, 0, 0);
            ac = __builtin_amdgcn_mfma_f32_16x16x32_bf16(wa5, bx1.s, ac, 0, 0, 0);
            if (vst) *(floatx4*)(op + 32 + q4 * 4) = ac;
            ac = floatx4{0.f, 0.f, 0.f, 0.f};
            ac = __builtin_amdgcn_mfma_f32_16x16x32_bf16(wa6, bx0.s, ac, 0, 0, 0);
            ac = __builtin_amdgcn_mfma_f32_16x16x32_bf16(wa7, bx1.s, ac, 0, 0, 0);
            if (vst) *(floatx4*)(op + 48 + q4 * 4) = ac;
        }

        // ---- irrep1: per d, 2 M-tiles; 12 consecutive floats as 3x float4 ----
        {
            floatx4 a1[2][3];
#pragma unroll
            for (int d = 0; d < 3; ++d) {
                floatx4 z = {0.f, 0.f, 0.f, 0.f};
                a1[0][d] = __builtin_amdgcn_mfma_f32_16x16x32_bf16(wc0, b1d[d].s, z, 0, 0, 0);
                a1[1][d] = __builtin_amdgcn_mfma_f32_16x16x32_bf16(wc1, b1d[d].s, z, 0, 0, 0);
            }
            if (vst) {
#pragma unroll
                for (int h = 0; h < 2; ++h) {
                    float* o1 = op + 64 + (h * 16 + q4 * 4) * 3;
                    floatx4 v0 = {a1[h][0][0], a1[h][1][0], a1[h][2][0], a1[h][0][1]};
                    floatx4 v1 = {a1[h][1][1], a1[h][2][1], a1[h][0][2], a1[h][1][2]};
                    floatx4 v2 = {a1[h][2][2], a1[h][0][3], a1[h][1][3], a1[h][2][3]};
                    *(floatx4*)(o1)     = v0;
                    *(floatx4*)(o1 + 4) = v1;
                    *(floatx4*)(o1 + 8) = v2;
                }
            }
        }

        // ---- irrep2: per d, M=16 K=16 (w-side zero-padded to K=32); 5x float4 ----
        {
            floatx4 a2[5];
#pragma unroll
            for (int d = 0; d < 5; ++d) {
                floatx4 z = {0.f, 0.f, 0.f, 0.f};
                a2[d] = __builtin_amdgcn_mfma_f32_16x16x32_bf16(wc2, b2d[d].s, z, 0, 0, 0);
            }
            if (vst) {
                float* o2 = op + 160 + q4 * 20;
                floatx4 v0 = {a2[0][0], a2[1][0], a2[2][0], a2[3][0]};
                floatx4 v1 = {a2[4][0], a2[0][1], a2[1][1], a2[2][1]};
                floatx4 v2 = {a2[3][1], a2[4][1], a2[0][2], a2[1][2]};
                floatx4 v3 = {a2[2][2], a2[3][2], a2[4][2], a2[0][3]};
                floatx4 v4 = {a2[1][3], a2[2][3], a2[3][3], a2[4][3]};
                *(floatx4*)(o2)      = v0;
                *(floatx4*)(o2 + 4)  = v1;
                *(floatx4*)(o2 + 8)  = v2;
                *(floatx4*)(o2 + 12) = v3;
                *(floatx4*)(o2 + 16) = v4;
            }
        }

        m = m2;
        if (!m) break;
        const int tyn = __shfl(pl, __builtin_ctz(m)) >> 24;   // rare: next segment
        LOAD_FRAGS(wt + (size_t)tyn * WT_STRIDE);
    }
}

extern "C" void kernel_launch(void* const* d_in, const int* in_sizes, int n_in,
                              void* d_out, int out_size, void* d_ws, size_t ws_size,
                              hipStream_t stream) {
    const float* x  = (const float*)d_in[0];
    const float* W0 = (const float*)d_in[1];
    const float* W1 = (const float*)d_in[2];
    const float* W2 = (const float*)d_in[3];
    const int*   idx = (const int*)d_in[4];
    float* out = (float*)d_out;
    const int n = in_sizes[4];                    // 65536 nodes
    const int nb = (n + 255) / 256;

    char* ws = (char*)d_ws;
    unsigned short* wt = (unsigned short*)ws;     // 720896 B
    size_t off = (size_t)NTYPES * WT_STRIDE * 2;
    int* psort = (int*)(ws + off); off += (size_t)n * 4;
    int* bh    = (int*)(ws + off); off += (size_t)NTYPES * NTYPES * 4;
    int* gcur  = (int*)(ws + off);

    wt_kernel     <<<NTYPES, 256, 0, stream>>>(W0, W1, W2, idx, wt, bh, n);
    base_kernel   <<<1, 64, 0, stream>>>(bh, gcur);
    scatter_kernel<<<nb, 256, 0, stream>>>(idx, gcur, psort, n);
    main_kernel   <<<(n + WROWS - 1) / WROWS, 64, 0, stream>>>(x, psort, wt, out, n);
}